// Round 4
// baseline (551.428 us; speedup 1.0000x reference)
//
#include <hip/hip_runtime.h>

constexpr int N   = 100000;   // nodes
constexpr int E   = 1600000;  // message edges
constexpr int EP  = 200000;   // pos scored edges
constexpr int ES  = 400000;   // total scored edges (pos+neg)
constexpr int CAP = 64;       // per-node in-edge bucket capacity (Poisson(16): P(deg>=64)~1e-18)
constexpr int XG  = 8;        // XCD groups for dst-partitioned bucket fill
constexpr int DRANGE = (N + XG - 1) / XG;   // 12500 nodes per group

typedef _Float16 f16x8 __attribute__((ext_vector_type(8)));
typedef _Float16 f16x4 __attribute__((ext_vector_type(4)));
typedef float    f32x4 __attribute__((ext_vector_type(4)));

// ---------------------------------------------------------------- bucket fill
// XCD-routed: blockIdx%8 round-robins XCDs (perf heuristic only); group g
// claims dst in [g*12500,(g+1)*12500) so each bucket line is written by one
// XCD's L2 -> ~16 writes merge, one writeback per line.
__global__ __launch_bounds__(256) void fill_buckets(const int* __restrict__ ei,
                                                    int* __restrict__ cnt,
                                                    int* __restrict__ col) {
    const int g     = blockIdx.x & (XG - 1);
    const int chunk = blockIdx.x >> 3;          // 0..6249
    const int e     = chunk * 256 + threadIdx.x;
    const int d     = ei[E + e];                // edge_index[1] = dst
    const unsigned rel = (unsigned)(d - g * DRANGE);
    if (rel < (unsigned)DRANGE) {
        const int s = ei[e];                    // edge_index[0] = src
        const int p = atomicAdd(&cnt[d], 1);
        if (p < CAP) col[d * CAP + p] = s;
    }
}

// ---------------------------------------------------------------- GEMM1 (f16 MFMA)
// H[100000,128](f16) = X[100000,256](f32->f16) @ W1[256,128](f32->f16), fp32 accum.
__global__ __launch_bounds__(256) void gemm1_mfma(const float* __restrict__ X,
                                                  const float* __restrict__ W1,
                                                  _Float16* __restrict__ H) {
    __shared__ _Float16 As[128][40];   // [m][k], stride 40 f16 = 80 B
    __shared__ _Float16 Bs[128][40];   // [n][k]  (W1 tile transposed)

    const int tid  = threadIdx.x;
    const int wave = tid >> 6;
    const int lane = tid & 63;
    const int m16  = lane & 15;
    const int quad = lane >> 4;
    const int blockRow = blockIdx.x * 128;

    f32x4 acc[2][8] = {};

    for (int k0 = 0; k0 < 256; k0 += 32) {
        __syncthreads();
#pragma unroll
        for (int i = 0; i < 4; ++i) {
            int f  = tid + 256 * i;
            int r  = f >> 3;
            int kq = f & 7;
            int gr = blockRow + r;
            float4 v = (gr < N) ? *(const float4*)&X[(size_t)gr * 256 + k0 + kq * 4]
                                : make_float4(0.f, 0.f, 0.f, 0.f);
            f16x4 h4;
            h4[0] = (_Float16)v.x; h4[1] = (_Float16)v.y;
            h4[2] = (_Float16)v.z; h4[3] = (_Float16)v.w;
            *(f16x4*)&As[r][kq * 4] = h4;
        }
#pragma unroll
        for (int i = 0; i < 4; ++i) {
            int f  = tid + 256 * i;
            int k  = f >> 5;
            int n4 = f & 31;
            float4 v = *(const float4*)&W1[(size_t)(k0 + k) * 128 + n4 * 4];
            Bs[n4 * 4 + 0][k] = (_Float16)v.x;
            Bs[n4 * 4 + 1][k] = (_Float16)v.y;
            Bs[n4 * 4 + 2][k] = (_Float16)v.z;
            Bs[n4 * 4 + 3][k] = (_Float16)v.w;
        }
        __syncthreads();
        f16x8 afrag[2];
#pragma unroll
        for (int mt = 0; mt < 2; ++mt)
            afrag[mt] = *(const f16x8*)&As[wave * 32 + mt * 16 + m16][quad * 8];
#pragma unroll
        for (int nt = 0; nt < 8; ++nt) {
            f16x8 bfrag = *(const f16x8*)&Bs[nt * 16 + m16][quad * 8];
            acc[0][nt] = __builtin_amdgcn_mfma_f32_16x16x32_f16(afrag[0], bfrag, acc[0][nt], 0, 0, 0);
            acc[1][nt] = __builtin_amdgcn_mfma_f32_16x16x32_f16(afrag[1], bfrag, acc[1][nt], 0, 0, 0);
        }
    }
#pragma unroll
    for (int mt = 0; mt < 2; ++mt) {
#pragma unroll
        for (int nt = 0; nt < 8; ++nt) {
#pragma unroll
            for (int r = 0; r < 4; ++r) {
                int gm = blockRow + wave * 32 + mt * 16 + quad * 4 + r;
                int gn = nt * 16 + m16;
                if (gm < N) H[(size_t)gm * 128 + gn] = (_Float16)acc[mt][nt][r];
            }
        }
    }
}

// ---------------------------------------------------------------- Fused agg1 + gemm2
// One wave per node. 16 lanes per H-row (16 B f16x8 per lane) -> 4 edges per
// step, unrolled x2 = 8 edges/iter, 2 independent dwordx4 loads in flight.
// Self-loop folded in as edge index c; pad slots have weight 0 on row n.
__global__ __launch_bounds__(256) void agg1_gemm2(const _Float16* __restrict__ H,
                                                  const int* __restrict__ cnt,
                                                  const int* __restrict__ col,
                                                  const float* __restrict__ b1,
                                                  const float* __restrict__ W2,
                                                  float* __restrict__ Z) {
    const int n    = (blockIdx.x * blockDim.x + threadIdx.x) >> 6;
    const int lane = threadIdx.x & 63;
    if (n >= N) return;
    const int c = min(cnt[n], CAP);
    const int q = lane >> 4;    // edge-group 0..3
    const int r = lane & 15;    // 16 B chunk within row: feats [8r, 8r+8)

    // lane j<c: edge j (src, dinv[src]); lane c: self-loop (n, dinv[n]); else w=0
    int sv = n;
    if (lane < c) sv = col[n * CAP + lane];
    const float dvw = rsqrtf((float)cnt[sv] + 1.0f);
    const float dv  = (lane <= c) ? dvw : 0.0f;

    float acc[8] = {};
    const int ned = c + 1;
    for (int j = 0; j < ned; j += 8) {
        const int e0 = j + q, e1 = j + q + 4;           // <= 63 always
        const int   s0 = __shfl(sv, e0);
        const float w0 = __shfl(dv, e0);
        const int   s1 = __shfl(sv, e1);
        const float w1 = __shfl(dv, e1);
        const f16x8 v0 = *(const f16x8*)&H[(size_t)s0 * 128 + r * 8];
        const f16x8 v1 = *(const f16x8*)&H[(size_t)s1 * 128 + r * 8];
#pragma unroll
        for (int i = 0; i < 8; ++i) {
            acc[i] = fmaf(w0, (float)v0[i], acc[i]);
            acc[i] = fmaf(w1, (float)v1[i], acc[i]);
        }
    }
    // combine the 4 edge-groups: lanes r, r+16, r+32, r+48 hold partials of feats [8r,8r+8)
#pragma unroll
    for (int off = 16; off <= 32; off <<= 1)
#pragma unroll
        for (int i = 0; i < 8; ++i) acc[i] += __shfl_xor(acc[i], off);

    const float dn = __shfl(dv, c);   // dinv[n]
    const float4 bA = *(const float4*)&b1[r * 8];
    const float4 bB = *(const float4*)&b1[r * 8 + 4];
    float hr[8];
    hr[0] = fmaxf(acc[0] * dn + bA.x, 0.f);
    hr[1] = fmaxf(acc[1] * dn + bA.y, 0.f);
    hr[2] = fmaxf(acc[2] * dn + bA.z, 0.f);
    hr[3] = fmaxf(acc[3] * dn + bA.w, 0.f);
    hr[4] = fmaxf(acc[4] * dn + bB.x, 0.f);
    hr[5] = fmaxf(acc[5] * dn + bB.y, 0.f);
    hr[6] = fmaxf(acc[6] * dn + bB.z, 0.f);
    hr[7] = fmaxf(acc[7] * dn + bB.w, 0.f);

    // gemm2 partial: lane covers W2 rows [8r, 8r+8)
    float p[8] = {};
#pragma unroll
    for (int i = 0; i < 8; ++i) {
        const float4 w0 = *(const float4*)&W2[(size_t)(r * 8 + i) * 8];
        const float4 w1 = *(const float4*)&W2[(size_t)(r * 8 + i) * 8 + 4];
        p[0] = fmaf(hr[i], w0.x, p[0]); p[1] = fmaf(hr[i], w0.y, p[1]);
        p[2] = fmaf(hr[i], w0.z, p[2]); p[3] = fmaf(hr[i], w0.w, p[3]);
        p[4] = fmaf(hr[i], w1.x, p[4]); p[5] = fmaf(hr[i], w1.y, p[5]);
        p[6] = fmaf(hr[i], w1.z, p[6]); p[7] = fmaf(hr[i], w1.w, p[7]);
    }
#pragma unroll
    for (int off = 1; off <= 8; off <<= 1)
#pragma unroll
        for (int o = 0; o < 8; ++o) p[o] += __shfl_xor(p[o], off);

    if (lane == 0) {
        *(float4*)&Z[(size_t)n * 8]     = make_float4(p[0], p[1], p[2], p[3]);
        *(float4*)&Z[(size_t)n * 8 + 4] = make_float4(p[4], p[5], p[6], p[7]);
    }
}

// ---------------------------------------------------------------- Aggregation layer 2 (F=8)
__global__ __launch_bounds__(256) void agg2(const float* __restrict__ Z,
                                            const int* __restrict__ cnt,
                                            const int* __restrict__ col,
                                            const float* __restrict__ b2,
                                            float* __restrict__ ZA) {
    const int n = blockIdx.x * blockDim.x + threadIdx.x;
    if (n >= N) return;
    const int c = min(cnt[n], CAP);
    float acc[8] = {};
    for (int j = 0; j < c; ++j) {
        const int s = col[n * CAP + j];
        const float w = rsqrtf((float)cnt[s] + 1.0f);
        const float4 z0 = *(const float4*)&Z[(size_t)s * 8];
        const float4 z1 = *(const float4*)&Z[(size_t)s * 8 + 4];
        acc[0] = fmaf(w, z0.x, acc[0]); acc[1] = fmaf(w, z0.y, acc[1]);
        acc[2] = fmaf(w, z0.z, acc[2]); acc[3] = fmaf(w, z0.w, acc[3]);
        acc[4] = fmaf(w, z1.x, acc[4]); acc[5] = fmaf(w, z1.y, acc[5]);
        acc[6] = fmaf(w, z1.z, acc[6]); acc[7] = fmaf(w, z1.w, acc[7]);
    }
    const float dn = rsqrtf((float)c + 1.0f);
    const float4 zn0 = *(const float4*)&Z[(size_t)n * 8];
    const float4 zn1 = *(const float4*)&Z[(size_t)n * 8 + 4];
    float o[8];
    o[0] = (acc[0] + dn * zn0.x) * dn + b2[0];
    o[1] = (acc[1] + dn * zn0.y) * dn + b2[1];
    o[2] = (acc[2] + dn * zn0.z) * dn + b2[2];
    o[3] = (acc[3] + dn * zn0.w) * dn + b2[3];
    o[4] = (acc[4] + dn * zn1.x) * dn + b2[4];
    o[5] = (acc[5] + dn * zn1.y) * dn + b2[5];
    o[6] = (acc[6] + dn * zn1.z) * dn + b2[6];
    o[7] = (acc[7] + dn * zn1.w) * dn + b2[7];
    *(float4*)&ZA[(size_t)n * 8]     = make_float4(o[0], o[1], o[2], o[3]);
    *(float4*)&ZA[(size_t)n * 8 + 4] = make_float4(o[4], o[5], o[6], o[7]);
}

// ---------------------------------------------------------------- Edge scoring
__global__ __launch_bounds__(256) void score(const float* __restrict__ ZA,
                                             const int* __restrict__ pe,
                                             const int* __restrict__ ne,
                                             float* __restrict__ out) {
    const int e = blockIdx.x * blockDim.x + threadIdx.x;
    if (e >= ES) return;
    int a, b;
    if (e < EP) { a = pe[e];      b = pe[EP + e]; }
    else        { a = ne[e - EP]; b = ne[e];      }
    const float4 xa0 = *(const float4*)&ZA[(size_t)a * 8];
    const float4 xa1 = *(const float4*)&ZA[(size_t)a * 8 + 4];
    const float4 xb0 = *(const float4*)&ZA[(size_t)b * 8];
    const float4 xb1 = *(const float4*)&ZA[(size_t)b * 8 + 4];
    out[e] = xa0.x * xb0.x + xa0.y * xb0.y + xa0.z * xb0.z + xa0.w * xb0.w +
             xa1.x * xb1.x + xa1.y * xb1.y + xa1.z * xb1.z + xa1.w * xb1.w;
}

// ---------------------------------------------------------------- launch

extern "C" void kernel_launch(void* const* d_in, const int* in_sizes, int n_in,
                              void* d_out, int out_size, void* d_ws, size_t ws_size,
                              hipStream_t stream) {
    const float* x  = (const float*)d_in[0];
    const int*   ei = (const int*)d_in[1];   // [2, 1.6M] row-major
    const int*   pe = (const int*)d_in[2];   // [2, 200k]
    const int*   ne = (const int*)d_in[3];   // [2, 200k]
    const float* W1 = (const float*)d_in[4];
    const float* b1 = (const float*)d_in[5];
    const float* W2 = (const float*)d_in[6];
    const float* b2 = (const float*)d_in[7];
    float* out = (float*)d_out;

    char* ws = (char*)d_ws;
    size_t off = 0;
    auto carve = [&](size_t bytes) {
        char* p = ws + off;
        off += (bytes + 255) & ~(size_t)255;
        return p;
    };
    int*       cnt  = (int*)      carve((size_t)N * sizeof(int));           // 0.4 MB
    int*       col  = (int*)      carve((size_t)N * CAP * sizeof(int));     // 25.6 MB
    _Float16*  H    = (_Float16*) carve((size_t)N * 128 * sizeof(_Float16));// 25.6 MB
    float*     Z    = (float*)    carve((size_t)N * 8 * sizeof(float));     // 3.2 MB
    float*     ZA   = (float*)    carve((size_t)N * 8 * sizeof(float));     // 3.2 MB

    hipMemsetAsync(cnt, 0, (size_t)N * sizeof(int), stream);
    fill_buckets<<<XG * (E / 256), 256, 0, stream>>>(ei, cnt, col);
    gemm1_mfma  <<<(N + 127) / 128, 256, 0, stream>>>(x, W1, H);
    agg1_gemm2  <<<(N * 64 + 255) / 256, 256, 0, stream>>>(H, cnt, col, b1, W2, Z);
    agg2        <<<(N + 255) / 256, 256, 0, stream>>>(Z, cnt, col, b2, ZA);
    score       <<<(ES + 255) / 256, 256, 0, stream>>>(ZA, pe, ne, out);
}

// Round 5
// 445.306 us; speedup vs baseline: 1.2383x; 1.2383x over previous
//
#include <hip/hip_runtime.h>

constexpr int N   = 100000;   // nodes
constexpr int E   = 1600000;  // message edges
constexpr int EP  = 200000;   // pos scored edges
constexpr int ES  = 400000;   // total scored edges (pos+neg)
constexpr int CAP = 64;       // per-node in-edge bucket capacity (Poisson(16): P(deg>=64)~1e-18)
constexpr int XG  = 8;        // XCD groups for dst-partitioned bucket fill
constexpr int DRANGE = (N + XG - 1) / XG;   // 12500 nodes per group

typedef _Float16 f16x8 __attribute__((ext_vector_type(8)));
typedef _Float16 f16x4 __attribute__((ext_vector_type(4)));
typedef _Float16 f16x2 __attribute__((ext_vector_type(2)));
typedef float    f32x4 __attribute__((ext_vector_type(4)));

// ---------------------------------------------------------------- bucket fill
// XCD-routed: blockIdx%8 round-robins XCDs (perf heuristic only); group g
// claims dst in [g*12500,(g+1)*12500) so each bucket line is written by one
// XCD's L2 -> ~16 writes merge, one writeback per line.
__global__ __launch_bounds__(256) void fill_buckets(const int* __restrict__ ei,
                                                    int* __restrict__ cnt,
                                                    int* __restrict__ col) {
    const int g     = blockIdx.x & (XG - 1);
    const int chunk = blockIdx.x >> 3;          // 0..6249
    const int e     = chunk * 256 + threadIdx.x;
    const int d     = ei[E + e];                // edge_index[1] = dst
    const unsigned rel = (unsigned)(d - g * DRANGE);
    if (rel < (unsigned)DRANGE) {
        const int s = ei[e];                    // edge_index[0] = src
        const int p = atomicAdd(&cnt[d], 1);
        if (p < CAP) col[d * CAP + p] = s;
    }
}

// ---------------------------------------------------------------- GEMM1 (f16 MFMA)
// H[100000,128](f16) = X[100000,256](f32->f16) @ W1[256,128](f32->f16), fp32 accum.
__global__ __launch_bounds__(256) void gemm1_mfma(const float* __restrict__ X,
                                                  const float* __restrict__ W1,
                                                  _Float16* __restrict__ H) {
    __shared__ _Float16 As[128][40];   // [m][k], stride 40 f16 = 80 B
    __shared__ _Float16 Bs[128][40];   // [n][k]  (W1 tile transposed)

    const int tid  = threadIdx.x;
    const int wave = tid >> 6;
    const int lane = tid & 63;
    const int m16  = lane & 15;
    const int quad = lane >> 4;
    const int blockRow = blockIdx.x * 128;

    f32x4 acc[2][8] = {};

    for (int k0 = 0; k0 < 256; k0 += 32) {
        __syncthreads();
#pragma unroll
        for (int i = 0; i < 4; ++i) {
            int f  = tid + 256 * i;
            int r  = f >> 3;
            int kq = f & 7;
            int gr = blockRow + r;
            float4 v = (gr < N) ? *(const float4*)&X[(size_t)gr * 256 + k0 + kq * 4]
                                : make_float4(0.f, 0.f, 0.f, 0.f);
            f16x4 h4;
            h4[0] = (_Float16)v.x; h4[1] = (_Float16)v.y;
            h4[2] = (_Float16)v.z; h4[3] = (_Float16)v.w;
            *(f16x4*)&As[r][kq * 4] = h4;
        }
#pragma unroll
        for (int i = 0; i < 4; ++i) {
            int f  = tid + 256 * i;
            int k  = f >> 5;
            int n4 = f & 31;
            float4 v = *(const float4*)&W1[(size_t)(k0 + k) * 128 + n4 * 4];
            Bs[n4 * 4 + 0][k] = (_Float16)v.x;
            Bs[n4 * 4 + 1][k] = (_Float16)v.y;
            Bs[n4 * 4 + 2][k] = (_Float16)v.z;
            Bs[n4 * 4 + 3][k] = (_Float16)v.w;
        }
        __syncthreads();
        f16x8 afrag[2];
#pragma unroll
        for (int mt = 0; mt < 2; ++mt)
            afrag[mt] = *(const f16x8*)&As[wave * 32 + mt * 16 + m16][quad * 8];
#pragma unroll
        for (int nt = 0; nt < 8; ++nt) {
            f16x8 bfrag = *(const f16x8*)&Bs[nt * 16 + m16][quad * 8];
            acc[0][nt] = __builtin_amdgcn_mfma_f32_16x16x32_f16(afrag[0], bfrag, acc[0][nt], 0, 0, 0);
            acc[1][nt] = __builtin_amdgcn_mfma_f32_16x16x32_f16(afrag[1], bfrag, acc[1][nt], 0, 0, 0);
        }
    }
#pragma unroll
    for (int mt = 0; mt < 2; ++mt) {
#pragma unroll
        for (int nt = 0; nt < 8; ++nt) {
#pragma unroll
            for (int r = 0; r < 4; ++r) {
                int gm = blockRow + wave * 32 + mt * 16 + quad * 4 + r;
                int gn = nt * 16 + m16;
                if (gm < N) H[(size_t)gm * 128 + gn] = (_Float16)acc[mt][nt][r];
            }
        }
    }
}

// ---------------------------------------------------------------- Fused agg1 + gemm2
// One wave per node; lane l owns feats [2l, 2l+1] (round-3 layout, proven
// coalescing: one contiguous 256 B row per load instruction). NEW: depth-4
// double-buffered software prefetch -> 4 independent row loads in flight
// per wave (Little's law: 4x in-flight bytes vs round 3).
// Edge list per wave: index j<c -> col src; j==c -> self loop (n); j>c -> w=0
// (sv=n, harmless cached read). Shuffle index clamped to 63 (dv=0 there).
__global__ __launch_bounds__(256) void agg1_gemm2(const _Float16* __restrict__ H,
                                                  const int* __restrict__ cnt,
                                                  const int* __restrict__ col,
                                                  const float* __restrict__ b1,
                                                  const float* __restrict__ W2,
                                                  float* __restrict__ Z) {
    const int n    = (blockIdx.x * blockDim.x + threadIdx.x) >> 6;
    const int lane = threadIdx.x & 63;
    if (n >= N) return;
    const int c = min(cnt[n], CAP);

    int sv = n;
    if (lane < c) sv = col[n * CAP + lane];
    const float dvw = rsqrtf((float)cnt[sv] + 1.0f);
    const float dv  = (lane <= c) ? dvw : 0.0f;

    const _Float16* hbase = H + lane * 2;
    const int ned4 = (c + 1 + 3) & ~3;      // quads of 4 edges

    f16x2 va[4]; float wa[4];
#pragma unroll
    for (int t = 0; t < 4; ++t) {
        const int   e = min(t, 63);
        const int   s = __shfl(sv, e);
        wa[t]         = __shfl(dv, e);
        va[t] = *(const f16x2*)&hbase[(size_t)s * 128];
    }
    float ax = 0.f, ay = 0.f;
    for (int j = 4; j < ned4; j += 4) {
        f16x2 vb[4]; float wb[4];
#pragma unroll
        for (int t = 0; t < 4; ++t) {       // issue next quad's 4 loads
            const int   e = min(j + t, 63);
            const int   s = __shfl(sv, e);
            wb[t]         = __shfl(dv, e);
            vb[t] = *(const f16x2*)&hbase[(size_t)s * 128];
        }
#pragma unroll
        for (int t = 0; t < 4; ++t) {       // consume current quad
            ax = fmaf(wa[t], (float)va[t][0], ax);
            ay = fmaf(wa[t], (float)va[t][1], ay);
            va[t] = vb[t]; wa[t] = wb[t];
        }
    }
#pragma unroll
    for (int t = 0; t < 4; ++t) {           // drain last quad
        ax = fmaf(wa[t], (float)va[t][0], ax);
        ay = fmaf(wa[t], (float)va[t][1], ay);
    }

    const float dn = __shfl(dv, c);         // dinv[n]
    const float2 b = *(const float2*)&b1[lane * 2];
    const float hr0 = fmaxf(ax * dn + b.x, 0.f);
    const float hr1 = fmaxf(ay * dn + b.y, 0.f);

    // gemm2 partial: lane covers W2 rows 2l, 2l+1
    const float4 wa0 = *(const float4*)&W2[(size_t)(lane * 2) * 8];
    const float4 wa1 = *(const float4*)&W2[(size_t)(lane * 2) * 8 + 4];
    const float4 wb0 = *(const float4*)&W2[(size_t)(lane * 2 + 1) * 8];
    const float4 wb1 = *(const float4*)&W2[(size_t)(lane * 2 + 1) * 8 + 4];
    float p[8];
    p[0] = hr0 * wa0.x + hr1 * wb0.x;
    p[1] = hr0 * wa0.y + hr1 * wb0.y;
    p[2] = hr0 * wa0.z + hr1 * wb0.z;
    p[3] = hr0 * wa0.w + hr1 * wb0.w;
    p[4] = hr0 * wa1.x + hr1 * wb1.x;
    p[5] = hr0 * wa1.y + hr1 * wb1.y;
    p[6] = hr0 * wa1.z + hr1 * wb1.z;
    p[7] = hr0 * wa1.w + hr1 * wb1.w;
#pragma unroll
    for (int off = 32; off > 0; off >>= 1) {
#pragma unroll
        for (int j = 0; j < 8; ++j) p[j] += __shfl_xor(p[j], off);
    }
    if (lane == 0) {
        *(float4*)&Z[(size_t)n * 8]     = make_float4(p[0], p[1], p[2], p[3]);
        *(float4*)&Z[(size_t)n * 8 + 4] = make_float4(p[4], p[5], p[6], p[7]);
    }
}

// ---------------------------------------------------------------- Aggregation layer 2 (F=8)
// One thread per node, depth-4 prefetch of (src, Z-row) to overlap misses.
__global__ __launch_bounds__(256) void agg2(const float* __restrict__ Z,
                                            const int* __restrict__ cnt,
                                            const int* __restrict__ col,
                                            const float* __restrict__ b2,
                                            float* __restrict__ ZA) {
    const int n = blockIdx.x * blockDim.x + threadIdx.x;
    if (n >= N) return;
    const int c = min(cnt[n], CAP);
    float acc[8] = {};

    float4 va0[4], va1[4]; float wv[4];
#pragma unroll
    for (int t = 0; t < 4; ++t) {
        const int s = (t < c) ? col[n * CAP + t] : n;
        wv[t]  = (t < c) ? rsqrtf((float)cnt[s] + 1.0f) : 0.0f;
        va0[t] = *(const float4*)&Z[(size_t)s * 8];
        va1[t] = *(const float4*)&Z[(size_t)s * 8 + 4];
    }
    int j = 4;
    for (; j + 4 <= c + 4; j += 4) {
        float4 vb0[4], vb1[4]; float wb[4];
#pragma unroll
        for (int t = 0; t < 4; ++t) {
            const int jt = j + t;
            const int s  = (jt < c) ? col[n * CAP + jt] : n;
            wb[t]  = (jt < c) ? rsqrtf((float)cnt[s] + 1.0f) : 0.0f;
            vb0[t] = *(const float4*)&Z[(size_t)s * 8];
            vb1[t] = *(const float4*)&Z[(size_t)s * 8 + 4];
        }
#pragma unroll
        for (int t = 0; t < 4; ++t) {
            const float w = wv[t];
            acc[0] = fmaf(w, va0[t].x, acc[0]); acc[1] = fmaf(w, va0[t].y, acc[1]);
            acc[2] = fmaf(w, va0[t].z, acc[2]); acc[3] = fmaf(w, va0[t].w, acc[3]);
            acc[4] = fmaf(w, va1[t].x, acc[4]); acc[5] = fmaf(w, va1[t].y, acc[5]);
            acc[6] = fmaf(w, va1[t].z, acc[6]); acc[7] = fmaf(w, va1[t].w, acc[7]);
            va0[t] = vb0[t]; va1[t] = vb1[t]; wv[t] = wb[t];
        }
    }
#pragma unroll
    for (int t = 0; t < 4; ++t) {
        const float w = wv[t];
        acc[0] = fmaf(w, va0[t].x, acc[0]); acc[1] = fmaf(w, va0[t].y, acc[1]);
        acc[2] = fmaf(w, va0[t].z, acc[2]); acc[3] = fmaf(w, va0[t].w, acc[3]);
        acc[4] = fmaf(w, va1[t].x, acc[4]); acc[5] = fmaf(w, va1[t].y, acc[5]);
        acc[6] = fmaf(w, va1[t].z, acc[6]); acc[7] = fmaf(w, va1[t].w, acc[7]);
    }

    const float dn = rsqrtf((float)c + 1.0f);
    const float4 zn0 = *(const float4*)&Z[(size_t)n * 8];
    const float4 zn1 = *(const float4*)&Z[(size_t)n * 8 + 4];
    float o[8];
    o[0] = (acc[0] + dn * zn0.x) * dn + b2[0];
    o[1] = (acc[1] + dn * zn0.y) * dn + b2[1];
    o[2] = (acc[2] + dn * zn0.z) * dn + b2[2];
    o[3] = (acc[3] + dn * zn0.w) * dn + b2[3];
    o[4] = (acc[4] + dn * zn1.x) * dn + b2[4];
    o[5] = (acc[5] + dn * zn1.y) * dn + b2[5];
    o[6] = (acc[6] + dn * zn1.z) * dn + b2[6];
    o[7] = (acc[7] + dn * zn1.w) * dn + b2[7];
    *(float4*)&ZA[(size_t)n * 8]     = make_float4(o[0], o[1], o[2], o[3]);
    *(float4*)&ZA[(size_t)n * 8 + 4] = make_float4(o[4], o[5], o[6], o[7]);
}

// ---------------------------------------------------------------- Edge scoring
__global__ __launch_bounds__(256) void score(const float* __restrict__ ZA,
                                             const int* __restrict__ pe,
                                             const int* __restrict__ ne,
                                             float* __restrict__ out) {
    const int e = blockIdx.x * blockDim.x + threadIdx.x;
    if (e >= ES) return;
    int a, b;
    if (e < EP) { a = pe[e];      b = pe[EP + e]; }
    else        { a = ne[e - EP]; b = ne[e];      }
    const float4 xa0 = *(const float4*)&ZA[(size_t)a * 8];
    const float4 xa1 = *(const float4*)&ZA[(size_t)a * 8 + 4];
    const float4 xb0 = *(const float4*)&ZA[(size_t)b * 8];
    const float4 xb1 = *(const float4*)&ZA[(size_t)b * 8 + 4];
    out[e] = xa0.x * xb0.x + xa0.y * xb0.y + xa0.z * xb0.z + xa0.w * xb0.w +
             xa1.x * xb1.x + xa1.y * xb1.y + xa1.z * xb1.z + xa1.w * xb1.w;
}

// ---------------------------------------------------------------- launch

extern "C" void kernel_launch(void* const* d_in, const int* in_sizes, int n_in,
                              void* d_out, int out_size, void* d_ws, size_t ws_size,
                              hipStream_t stream) {
    const float* x  = (const float*)d_in[0];
    const int*   ei = (const int*)d_in[1];   // [2, 1.6M] row-major
    const int*   pe = (const int*)d_in[2];   // [2, 200k]
    const int*   ne = (const int*)d_in[3];   // [2, 200k]
    const float* W1 = (const float*)d_in[4];
    const float* b1 = (const float*)d_in[5];
    const float* W2 = (const float*)d_in[6];
    const float* b2 = (const float*)d_in[7];
    float* out = (float*)d_out;

    char* ws = (char*)d_ws;
    size_t off = 0;
    auto carve = [&](size_t bytes) {
        char* p = ws + off;
        off += (bytes + 255) & ~(size_t)255;
        return p;
    };
    int*       cnt  = (int*)      carve((size_t)N * sizeof(int));           // 0.4 MB
    int*       col  = (int*)      carve((size_t)N * CAP * sizeof(int));     // 25.6 MB
    _Float16*  H    = (_Float16*) carve((size_t)N * 128 * sizeof(_Float16));// 25.6 MB
    float*     Z    = (float*)    carve((size_t)N * 8 * sizeof(float));     // 3.2 MB
    float*     ZA   = (float*)    carve((size_t)N * 8 * sizeof(float));     // 3.2 MB

    hipMemsetAsync(cnt, 0, (size_t)N * sizeof(int), stream);
    fill_buckets<<<XG * (E / 256), 256, 0, stream>>>(ei, cnt, col);
    gemm1_mfma  <<<(N + 127) / 128, 256, 0, stream>>>(x, W1, H);
    agg1_gemm2  <<<(N * 64 + 255) / 256, 256, 0, stream>>>(H, cnt, col, b1, W2, Z);
    agg2        <<<(N + 255) / 256, 256, 0, stream>>>(Z, cnt, col, b2, ZA);
    score       <<<(ES + 255) / 256, 256, 0, stream>>>(ZA, pe, ne, out);
}